// Round 6
// baseline (450.673 us; speedup 1.0000x reference)
//
#include <hip/hip_runtime.h>

// Problem dims: T=256, B=128, I=512, H=512
#define T_STEPS 256
#define B_DIM   128
#define I_DIM   512
#define H_DIM   512
#define M_DIM   (T_STEPS * B_DIM)   // 32768

// BIT-EXACTNESS CONSTRAINT (learned rounds 4/5): the reference GEMM is
// sequential-k fp32 FMA per output element; spike outputs flip on ~1e-7
// h perturbations (16.7M threshold crossings, min margin ~1.7e-7). Any
// summation reorder (MFMA limb schemes, split-K) produces ~6e-7 noise ->
// ~3 flips -> fail. So: fp32 VALU GEMM, k strictly ascending per output,
// single-rounding fma, bias added once at the end. Rounds 1-3 passed with
// absmax exactly 0.0 this way.

// GEMM tiling: 128x256 block tile, 256 threads, 8m x 16n per thread.
// Per-thread LDS traffic: 6 ds_read_b128 per k for 64 pk-FMA (vs round-3's
// 4 per 32) -> chip LDS-pipe 295k cy/CU vs FMA-pipe 262k cy/CU (balanced;
// round 3 was LDS-bound at 393k).
#define BM 128
#define BN 256
#define BK 32
#define LDRA 148   // A rows: loc(col)=col+4*(col>>5), col<128 -> max 139+xor12 -> 148
#define LDRB 288   // B rows: col<256 -> loc max 283+align -> 288

typedef float v2f __attribute__((ext_vector_type(2)));

// Swizzle (round-3 verified): element (k, col) at [k*LDR + P(k,col)],
// P(k,col) = (col + 4*(col>>5)) ^ (4*((k>>3)&3)).
// Reads: A-frags 4-addr broadcast (free), B-frags 2-way (free, m136).
__global__ __launch_bounds__(256, 2) void gemm_bias_f32(
    const float* __restrict__ A,
    const float* __restrict__ Bw,
    const float* __restrict__ bias,
    float* __restrict__ C)
{
    __shared__ float As[BK * LDRA];   // 18.5 KB
    __shared__ float Bs[BK * LDRB];   // 36 KB

    const int tid = threadIdx.x;
    const int tx  = tid & 15;   // n-group: n = 16*tx .. +15
    const int ty  = tid >> 4;   // m-group: m = 8*ty .. +7
    const int m0  = blockIdx.y * BM;
    const int n0  = blockIdx.x * BN;

    v2f acc[8][8];   // [mi][nj-pair]: n = 16*tx + 2*j, +1
    #pragma unroll
    for (int i = 0; i < 8; i++)
        #pragma unroll
        for (int j = 0; j < 8; j++)
            acc[i][j] = (v2f){0.0f, 0.0f};

    // Staging: A 4 float4/thread (rows lrow+32p, p<4), B 8 float4 (p<8).
    const int lrow = tid >> 3;        // 0..31
    const int lk   = (tid & 7) * 4;   // 0,4,...,28
    const int s_t  = 4 * ((lk >> 3) & 3);   // store-side XOR

    const int tyloc = 8 * ty + 4 * (ty >> 2);    // loc(8*ty)
    const int txloc = 16 * tx + 4 * (tx >> 1);   // loc(16*tx)

    const float* Aptr = A  + (size_t)(m0 + lrow) * I_DIM + lk;
    const float* Bptr = Bw + (size_t)(n0 + lrow) * I_DIM + lk;

    float4 av[4], bv[8];
    #pragma unroll
    for (int p = 0; p < 4; p++)
        av[p] = *(const float4*)(Aptr + (size_t)(p * 32) * I_DIM);
    #pragma unroll
    for (int p = 0; p < 8; p++)
        bv[p] = *(const float4*)(Bptr + (size_t)(p * 32) * I_DIM);

    for (int k0 = 0; k0 < I_DIM; k0 += BK) {
        __syncthreads();   // previous iteration's LDS reads complete

        #pragma unroll
        for (int p = 0; p < 4; p++) {
            const int col = (lrow + 36 * p) ^ s_t;   // loc(lrow+32p) ^ s_t
            float* a = &As[lk * LDRA + col];
            a[0 * LDRA] = av[p].x;
            a[1 * LDRA] = av[p].y;
            a[2 * LDRA] = av[p].z;
            a[3 * LDRA] = av[p].w;
        }
        #pragma unroll
        for (int p = 0; p < 8; p++) {
            const int col = (lrow + 36 * p) ^ s_t;
            float* b = &Bs[lk * LDRB + col];
            b[0 * LDRB] = bv[p].x;
            b[1 * LDRB] = bv[p].y;
            b[2 * LDRB] = bv[p].z;
            b[3 * LDRB] = bv[p].w;
        }

        __syncthreads();

        // Register prefetch of next global tile (in flight across compute).
        if (k0 + BK < I_DIM) {
            #pragma unroll
            for (int p = 0; p < 4; p++)
                av[p] = *(const float4*)(Aptr + (size_t)(p * 32) * I_DIM + k0 + BK);
            #pragma unroll
            for (int p = 0; p < 8; p++)
                bv[p] = *(const float4*)(Bptr + (size_t)(p * 32) * I_DIM + k0 + BK);
        }

        #pragma unroll
        for (int k = 0; k < BK; k++) {
            const int s = 4 * ((k >> 3) & 3);   // compile-time per unrolled k
            const float4 a0 = *(const float4*)&As[k * LDRA + ((tyloc)     ^ s)];
            const float4 a1 = *(const float4*)&As[k * LDRA + ((tyloc + 4) ^ s)];
            float4 b4[4];
            #pragma unroll
            for (int c = 0; c < 4; c++)
                b4[c] = *(const float4*)&Bs[k * LDRB + ((txloc + 4 * c) ^ s)];

            const float aa[8] = {a0.x, a0.y, a0.z, a0.w, a1.x, a1.y, a1.z, a1.w};
            v2f bb[8];
            #pragma unroll
            for (int c = 0; c < 4; c++) {
                bb[2 * c]     = (v2f){b4[c].x, b4[c].y};
                bb[2 * c + 1] = (v2f){b4[c].z, b4[c].w};
            }

            #pragma unroll
            for (int i = 0; i < 8; i++) {
                const v2f as = (v2f){aa[i], aa[i]};
                #pragma unroll
                for (int j = 0; j < 8; j++)
                    acc[i][j] = __builtin_elementwise_fma(as, bb[j], acc[i][j]);
            }
        }
    }

    // Epilogue: h = acc + bias (single add, matches ref), float4 stores.
    v2f bp[8];
    #pragma unroll
    for (int j = 0; j < 8; j++) {
        const int n = n0 + 16 * tx + 2 * j;
        bp[j] = (v2f){bias[n], bias[n + 1]};
    }

    #pragma unroll
    for (int i = 0; i < 8; i++) {
        const int m = m0 + 8 * ty + i;
        float* cp = C + (size_t)m * H_DIM + n0 + 16 * tx;
        #pragma unroll
        for (int q = 0; q < 4; q++) {
            const v2f o0 = acc[i][2 * q]     + bp[2 * q];
            const v2f o1 = acc[i][2 * q + 1] + bp[2 * q + 1];
            float4 o = {o0.x, o0.y, o1.x, o1.y};
            *(float4*)(cp + 4 * q) = o;
        }
    }
}

// LIF scan: v <- 0.5*v + h_t ; s = (v >= 1) ; v <- s ? 0 : v
// One thread per neuron (65536 = 4 waves/CU, grid-limited). Triple-buffered
// 16-deep chunks keep 32 loads (~32 KB/CU) in flight to cover ~900-cy HBM
// latency at this thin occupancy.
#define U 16
#define NC (T_STEPS / U)   // 16 chunks
__global__ __launch_bounds__(256) void lif_scan(
    const float* __restrict__ h,
    float* __restrict__ out)
{
    const int n   = B_DIM * H_DIM;   // 65536
    const int idx = blockIdx.x * 256 + threadIdx.x;
    const float* hp = h + idx;
    float* op = out + idx;

    float buf[3][U];
    #pragma unroll
    for (int i = 0; i < U; i++) buf[0][i] = hp[(size_t)i * n];
    #pragma unroll
    for (int i = 0; i < U; i++) buf[1][i] = hp[(size_t)(U + i) * n];

    float v = 0.0f;
    #pragma unroll
    for (int c = 0; c < NC; c++) {
        if (c + 2 < NC) {
            #pragma unroll
            for (int i = 0; i < U; i++)
                buf[(c + 2) % 3][i] = hp[(size_t)((c + 2) * U + i) * n];
        }
        #pragma unroll
        for (int i = 0; i < U; i++) {
            v = 0.5f * v + buf[c % 3][i];
            const bool fire = (v >= 1.0f);
            __builtin_nontemporal_store(fire ? 1.0f : 0.0f,
                                        &op[(size_t)(c * U + i) * n]);
            v = fire ? 0.0f : v;
        }
    }
}

extern "C" void kernel_launch(void* const* d_in, const int* in_sizes, int n_in,
                              void* d_out, int out_size, void* d_ws, size_t ws_size,
                              hipStream_t stream) {
    const float* x = (const float*)d_in[0];   // (T, B, I) fp32
    const float* W = (const float*)d_in[1];   // (H, I)    fp32
    const float* b = (const float*)d_in[2];   // (H,)      fp32
    float* out = (float*)d_out;               // (T, B, H) fp32 spikes
    float* h   = (float*)d_ws;                // (T*B, H)  fp32 scratch, 64 MB

    dim3 grid(H_DIM / BN, M_DIM / BM);        // (2, 256)
    gemm_bias_f32<<<grid, 256, 0, stream>>>(x, W, b, h);

    lif_scan<<<(B_DIM * H_DIM) / 256, 256, 0, stream>>>(h, out);
}